// Round 4
// baseline (229.120 us; speedup 1.0000x reference)
//
#include <hip/hip_runtime.h>
#include <hip/hip_bf16.h>
#include <cstdint>
#include <cstddef>

using bf16 = __hip_bfloat16;
typedef __attribute__((ext_vector_type(8))) short short8;
typedef __attribute__((ext_vector_type(4))) float floatx4;

#define B_ 4
#define T_ 2048
#define C_ 1024
#define H_ 16
#define HS_ 64
#define BT_ (B_*T_)
#define N3C (3*C_)

#define MFMA16(a,b,c) __builtin_amdgcn_mfma_f32_16x16x32_bf16((a),(b),(c),0,0,0)

#if __has_builtin(__builtin_amdgcn_exp2f)
#define EXP2(x) __builtin_amdgcn_exp2f(x)
#else
#define EXP2(x) exp2f(x)
#endif

static __device__ __forceinline__ void gld16(const bf16* g, bf16* l) {
  __builtin_amdgcn_global_load_lds(
      (const __attribute__((address_space(1))) unsigned int*)g,
      (__attribute__((address_space(3))) unsigned int*)l, 16, 0, 0);
}

static __device__ __forceinline__ unsigned short f2bf_us(float x) {
  bf16 b = __float2bfloat16(x);
  return *(unsigned short*)&b;
}

// ---------------- fused prep: cast x + transpose-cast both weights ----------
__global__ __launch_bounds__(256)
void k_prep(const float* __restrict__ x, bf16* __restrict__ xb,
            const float* __restrict__ Wqkv, bf16* __restrict__ wqkvT,
            const float* __restrict__ Wproj, bf16* __restrict__ wprojT)
{
  const int bid = blockIdx.x, tid = threadIdx.x;
  __shared__ float tile[64][65];

  if (bid < 4096) {
    const int i = bid*256 + tid;
    const float4 v0 = ((const float4*)x)[2*i];
    const float4 v1 = ((const float4*)x)[2*i + 1];
    union { bf16 b[8]; uint4 u; } cvt;
    cvt.b[0] = __float2bfloat16(v0.x);
    cvt.b[1] = __float2bfloat16(v0.y);
    cvt.b[2] = __float2bfloat16(v0.z);
    cvt.b[3] = __float2bfloat16(v0.w);
    cvt.b[4] = __float2bfloat16(v1.x);
    cvt.b[5] = __float2bfloat16(v1.y);
    cvt.b[6] = __float2bfloat16(v1.z);
    cvt.b[7] = __float2bfloat16(v1.w);
    ((uint4*)xb)[i] = cvt.u;
    return;
  }

  const float* in; bf16* out; int N, n0, k0;
  if (bid < 4864) {
    const int j = bid - 4096;
    in = Wqkv; out = wqkvT; N = N3C;
    n0 = (j % 48) * 64; k0 = (j / 48) * 64;
  } else {
    const int j = bid - 4864;
    in = Wproj; out = wprojT; N = C_;
    n0 = (j % 16) * 64; k0 = (j / 16) * 64;
  }
  const int r = tid >> 6, c = tid & 63;
  #pragma unroll
  for (int j = 0; j < 16; ++j)
    tile[r + j*4][c] = in[(size_t)(k0 + r + j*4) * N + n0 + c];
  __syncthreads();
  #pragma unroll
  for (int j = 0; j < 16; ++j) {
    int rr = r + j*4;
    out[(size_t)(n0 + rr) * C_ + k0 + c] = __float2bfloat16(tile[c][rr]);
  }
}

// ---------------- 256x256 QKV GEMM, BK=32, 4-buf counted-vmcnt pipeline -----
// R13: the deep-pipelined template with the VERIFIED swizzle.
//  - 8 waves as 2M x 4N; per-wave output 128x64 (8x4 frags): 12 LDS reads
//    per 32 MFMA (vs 8/16 of the 128^2 structure) - the read-ratio lever.
//  - 128 KiB static LDS = FOUR K-32 buffers per operand (4 x 8KB A + 4 x 8KB
//    B). Stage tile i+3 while computing tile i (2 gld16 per phase); at tile
//    top s_waitcnt vmcnt(8) retires tile i block-wide while i+1/i+2 stay in
//    flight (~6 phases of latency cover). Loads NEVER drain in the loop.
//  - 2 phases/tile: P0 = read B(4)+A(4) frags, stage A(i+3), 16 MFMA (m-half
//    0); barrier; P1 = read A(4) frags, stage B(i+3), 16 MFMA (m-half 1).
//    B-frags register-reused across phases. setprio(1) around MFMA (T5).
//  - swizzle (verified 0-conflict in R3): 64B rows, phys chunk = c^((r>>1)&3)
//    -> quarter-wave covers all 8 bank-groups exactly 2x. Staging stays
//    lane-linear via pre-swizzled global chunk gc=(t&3)^((ra>>1)&3).
//  - hazards: RAW = vmcnt(8) + s_barrier at tile top. WAR = buf[(i+3)&3]
//    last read at tile i-1, retired (lgkm) before that barrier.
//  - K ascending, one MFMA per K-32 -> accumulation order identical to R1.
// Epilogue: nb<4 -> Q (pre-scaled), 4-7 -> K, 8-11 -> V transpose via 4 LDS
// passes of 64 cols into key-permuted Vt [B,H,HS,T].
__global__ __launch_bounds__(512, 1)
void k_gemm256(const bf16* __restrict__ A, const bf16* __restrict__ Bt,
               bf16* __restrict__ Qb, bf16* __restrict__ Kb, bf16* __restrict__ Vt)
{
  __shared__ __align__(16) char smem[131072];
  bf16* const sA = (bf16*)smem;               // [4][8192]  256 rows x 32
  bf16* const sB = (bf16*)(smem + 65536);     // [4][8192]

  const int tid  = threadIdx.x;
  const int lane = tid & 63, wave = tid >> 6;
  const int quad = lane >> 4, l16 = lane & 15;
  const int wm = wave >> 2, wn = wave & 3;

  const int g = blockIdx.x;                   // 384 blocks
  const int xcd = g & 7;
  const int local = g >> 3;                   // 0..47
  const int nb = local % 12;
  const int mb = (local / 12) * 8 + xcd;      // 0..31
  const int m0 = mb * 256, n0 = nb * 256;

  // staging: thread t -> rows t>>2 and 128+(t>>2); phys chunk t&3 holds
  // global chunk (t&3)^((row>>1)&3)  ((row+128)>>1 keeps the same &3).
  const int ra = tid >> 2;
  const int gc = (tid & 3) ^ ((ra >> 1) & 3);
  const bf16* aptr = A  + (size_t)(m0 + ra) * C_ + gc*8;
  const bf16* bptr = Bt + (size_t)(n0 + ra) * C_ + gc*8;

  floatx4 acc[8][4] = {};
  const int swz = (l16 >> 1) & 3;
  const int aoff = (wm*128 + l16)*32 + (quad ^ swz)*8;   // + p*2048 + ii*512
  const int boff = (wn*64  + l16)*32 + (quad ^ swz)*8;   // + j*512

#define STAGE_A(t) { bf16* d = sA + ((t)&3)*8192;                       \
    gld16(aptr + (t)*32,            d + tid*8);                         \
    gld16(aptr + (size_t)128*C_ + (t)*32, d + 4096 + tid*8); }
#define STAGE_B(t) { bf16* d = sB + ((t)&3)*8192;                       \
    gld16(bptr + (t)*32,            d + tid*8);                         \
    gld16(bptr + (size_t)128*C_ + (t)*32, d + 4096 + tid*8); }

  // prologue: tiles 0..2 staged (12 loads in flight)
  STAGE_A(0); STAGE_B(0);
  STAGE_A(1); STAGE_B(1);
  STAGE_A(2); STAGE_B(2);

  #pragma unroll 1
  for (int i = 0; i < 32; ++i) {
    if (i < 30)       asm volatile("s_waitcnt vmcnt(8)" ::: "memory");
    else if (i == 30) asm volatile("s_waitcnt vmcnt(4)" ::: "memory");
    else              asm volatile("s_waitcnt vmcnt(0)" ::: "memory");
    asm volatile("s_barrier" ::: "memory");
    const bf16* sa = sA + (i & 3)*8192;
    const bf16* sb = sB + (i & 3)*8192;
    short8 bq[4], af[4];
    #pragma unroll
    for (int j = 0; j < 4; ++j)    bq[j]  = *(const short8*)&sb[boff + j*512];
    #pragma unroll
    for (int ii = 0; ii < 4; ++ii) af[ii] = *(const short8*)&sa[aoff + ii*512];
    if (i <= 28) STAGE_A(i+3);
    __builtin_amdgcn_s_setprio(1);
    #pragma unroll
    for (int ii = 0; ii < 4; ++ii)
      #pragma unroll
      for (int j = 0; j < 4; ++j)
        acc[ii][j] = MFMA16(af[ii], bq[j], acc[ii][j]);
    __builtin_amdgcn_s_setprio(0);
    asm volatile("s_barrier" ::: "memory");
    #pragma unroll
    for (int ii = 0; ii < 4; ++ii) af[ii] = *(const short8*)&sa[aoff + 2048 + ii*512];
    if (i <= 28) STAGE_B(i+3);
    __builtin_amdgcn_s_setprio(1);
    #pragma unroll
    for (int ii = 0; ii < 4; ++ii)
      #pragma unroll
      for (int j = 0; j < 4; ++j)
        acc[4+ii][j] = MFMA16(af[ii], bq[j], acc[4+ii][j]);
    __builtin_amdgcn_s_setprio(0);
  }
#undef STAGE_A
#undef STAGE_B

  if (nb >= 8) {
    // ---- V: 4 LDS passes of 64 cols -> key-permuted Vt [B,H,HS,T] ----
    __syncthreads();                      // all waves done with sA/sB
    unsigned short* epi = (unsigned short*)smem;   // [64 cc][264 tl-pad]
    const int b  = m0 >> 11;
    const int t0 = m0 & 2047;
    #pragma unroll 1
    for (int pass = 0; pass < 4; ++pass) {
      if (wn == pass) {
        #pragma unroll
        for (int ii = 0; ii < 8; ++ii) {
          const int tl = wm*128 + ii*16 + quad*4;
          #pragma unroll
          for (int j = 0; j < 4; ++j) {
            const int ccl = j*16 + l16;
            #pragma unroll
            for (int r = 0; r < 4; ++r)
              epi[ccl*264 + tl + r] = f2bf_us(acc[ii][j][r]);
          }
        }
      }
      __syncthreads();
      const int h = ((n0 - 2*C_) >> 6) + pass;
      #pragma unroll
      for (int it = 0; it < 16; ++it) {
        const int id = it*512 + tid;        // 0..8191 dword-pairs
        const int tp = id & 31;
        const int rest = id >> 5;           // 0..255
        const int tl64 = (rest & 3) * 64;
        const int ccl = rest >> 2;          // 0..63  (= d)
        const int k0p = tp + (tp & 16);     // keys (k0p,k0p+16) -> pos (2tp,2tp+1)
        const unsigned lo = epi[ccl*264 + tl64 + k0p];
        const unsigned hi = epi[ccl*264 + tl64 + k0p + 16];
        unsigned* row = (unsigned*)(Vt + ((size_t)(b*H_ + h) * HS_ + ccl) * T_);
        row[(t0 >> 1) + tl64/2 + tp] = lo | (hi << 16);
      }
      if (pass < 3) __syncthreads();
    }
  } else {
    #pragma unroll
    for (int ii = 0; ii < 8; ++ii) {
      const int rowb = m0 + wm*128 + ii*16 + quad*4;
      #pragma unroll
      for (int j = 0; j < 4; ++j) {
        const int col = n0 + wn*64 + j*16 + l16;
        const int h = (col >> 6) & 15, d = col & 63;
        #pragma unroll
        for (int r = 0; r < 4; ++r) {
          const float v = acc[ii][j][r];
          const int rr = rowb + r;
          const int bb = rr >> 11, t = rr & 2047;
          const size_t addr = (((size_t)(bb*H_ + h) * T_ + t) << 6) + d;
          if (nb < 4) {
            // fold 1/sqrt(64) * log2(e) so attention softmax can use exp2
            Qb[addr] = __float2bfloat16(v * 0.18033688f);
          } else {
            Kb[addr] = __float2bfloat16(v);
          }
        }
      }
    }
  }
}

// ---------------- GEMM: 128^2, BK=64 drain-barrier (proj only, proven R1) ---
template<int MODE, int NB>
__global__ __launch_bounds__(256, 2)
void k_gemm(const bf16* __restrict__ A, const bf16* __restrict__ Bt,
            int N, int K,
            bf16* __restrict__ Qb, bf16* __restrict__ Kb, bf16* __restrict__ Vt,
            float* __restrict__ Out, const float* __restrict__ bias)
{
  __shared__ __align__(16) char smem[65536];
  bf16* const sAb = (bf16*)smem;               // [2][8192]
  bf16* const sBb = (bf16*)(smem + 32768);     // [2][8192]

  const int tid  = threadIdx.x;
  const int lane = tid & 63, wave = tid >> 6;
  const int quad = lane >> 4, l16 = lane & 15;
  const int wm = wave >> 1, wn = wave & 1;

  const int g = blockIdx.x;
  const int xcd = g & 7;
  const int local = g >> 3;
  const int nb = local % NB;
  const int mb = (local / NB) * 8 + xcd;
  const int m0 = mb * 128, n0 = nb * 128;

  const int ra = tid >> 3;
  const int gc = (tid & 7) ^ (ra & 7);
  const bf16* aptr = A  + (size_t)(m0 + ra) * K + gc*8;
  const bf16* bptr = Bt + (size_t)(n0 + ra) * K + gc*8;
  const size_t rj = (size_t)32 * K;

  floatx4 acc[4][4] = {};
  const int KI = K >> 6;
  const int x7a = l16 & 7;

  for (int i = 0; i <= KI; ++i) {
    __syncthreads();
    if (i < KI) {
      const int k0 = i << 6;
      bf16* sa = sAb + (i & 1) * 8192;
      bf16* sb = sBb + (i & 1) * 8192;
      #pragma unroll
      for (int q2 = 0; q2 < 4; ++q2) {
        gld16(aptr + q2*rj + k0, sa + q2*2048 + tid*8);
        gld16(bptr + q2*rj + k0, sb + q2*2048 + tid*8);
      }
    }
    if (i == 0) continue;
    const bf16* sa = sAb + ((i-1) & 1) * 8192;
    const bf16* sb = sBb + ((i-1) & 1) * 8192;
    #pragma unroll
    for (int ks = 0; ks < 2; ++ks) {
      short8 af[4], bfm[4];
      #pragma unroll
      for (int ii = 0; ii < 4; ++ii)
        af[ii] = *(const short8*)&sa[(wm*64 + ii*16 + l16)*64 + ((ks*4 + quad) ^ x7a)*8];
      #pragma unroll
      for (int ii = 0; ii < 4; ++ii)
        bfm[ii] = *(const short8*)&sb[(wn*64 + ii*16 + l16)*64 + ((ks*4 + quad) ^ x7a)*8];
      #pragma unroll
      for (int ii = 0; ii < 4; ++ii)
        #pragma unroll
        for (int j = 0; j < 4; ++j)
          acc[ii][j] = MFMA16(af[ii], bfm[j], acc[ii][j]);
    }
  }

  #pragma unroll
  for (int i = 0; i < 4; ++i) {
    const int rowb = m0 + wm*64 + i*16 + quad*4;
    #pragma unroll
    for (int j = 0; j < 4; ++j) {
      const int col = n0 + wn*64 + j*16 + l16;
      #pragma unroll
      for (int r = 0; r < 4; ++r) {
        const float v = acc[i][j][r];
        const int rr = rowb + r;
        if (MODE == 1) {
          Out[(size_t)rr * N + col] = v + bias[col];
        }
      }
    }
  }
}

// ---------------- flash attention (causal) ----------------------------------
__global__ __launch_bounds__(256, 3)
void k_attn(const bf16* __restrict__ Q, const bf16* __restrict__ K,
            const bf16* __restrict__ Vt, bf16* __restrict__ att)
{
  __shared__ bf16 kbuf[2][64*64];   // [buf][key][dc^key&7]
  __shared__ bf16 vbuf[2][64*64];   // [buf][d][pc^d&7]  (positions, permuted)
  __shared__ bf16 pbuf[4][32*64];   // per-wave [q][(pc+q)&7 rotation]

  const int tid  = threadIdx.x;
  const int lane = tid & 63, wave = tid >> 6;
  const int quad = lane >> 4, l16 = lane & 15;
  const int x7 = l16 & 7;

  const int g  = blockIdx.x;              // 1024 blocks
  const int bh = (g & 7) * 8 + ((g >> 3) & 7);  // 16 blocks of a bh share XCD g&7
  const int qt = 15 - (g >> 6);           // q-tile index; heavy (qt=15) first
  const int b = bh >> 4, h = bh & 15;

  const bf16* Qp = Q  + (size_t)bh * T_ * HS_;
  const bf16* Kp = K  + (size_t)bh * T_ * HS_;
  const bf16* Vp = Vt + (size_t)bh * HS_ * T_;

  const int qbase = qt*128 + wave*32;
  const int ntk = 2*qt + 2;               // key tiles to process

  short8 qf[2][2];
  #pragma unroll
  for (int mt = 0; mt < 2; ++mt)
    #pragma unroll
    for (int ss = 0; ss < 2; ++ss)
      qf[mt][ss] = *(const short8*)(Qp + (size_t)(qbase + mt*16 + l16) * HS_ + ss*32 + quad*8);

  floatx4 o[2][4] = {};
  float lrow[2][4] = {};

  const bf16* kg[2]; const bf16* vg[2];
  int ldsoff[2];
  #pragma unroll
  for (int it = 0; it < 2; ++it) {
    const int c = it*256 + tid;
    const int row = c >> 3;
    const int col = (c & 7) ^ (row & 7);
    kg[it] = Kp + (size_t)row * HS_ + col*8;
    vg[it] = Vp + (size_t)row * T_ + col*8;
    ldsoff[it] = c*8;
  }

  bf16* pw = pbuf[wave];
  unsigned int* pw32 = (unsigned int*)pw;
  const int c0 = l16 >> 2;
  const int dwl = l16 & 3;

  for (int i = 0; i <= ntk; ++i) {
    __syncthreads();
    if (i < ntk) {
      const int stk0 = i * 64;
      bf16* kb = kbuf[i & 1];
      bf16* vb = vbuf[i & 1];
      #pragma unroll
      for (int it = 0; it < 2; ++it) {
        gld16(kg[it] + (size_t)stk0 * HS_, kb + ldsoff[it]);
        gld16(vg[it] + stk0,               vb + ldsoff[it]);
      }
    }
    if (i == 0) continue;
    const int tk  = i - 1;
    const int tk0 = tk * 64;
    if (tk0 > qbase + 31) continue;
    const bf16* kb = kbuf[tk & 1];
    const bf16* vb = vbuf[tk & 1];

    floatx4 s[2][4] = {};
    __builtin_amdgcn_s_setprio(1);
    #pragma unroll
    for (int nt = 0; nt < 4; ++nt) {
      const int key = nt*16 + l16;
      #pragma unroll
      for (int ss = 0; ss < 2; ++ss) {
        short8 kf = *(const short8*)&kb[(key*8 + ((ss*4+quad) ^ x7))*8];
        s[0][nt] = MFMA16(qf[0][ss], kf, s[0][nt]);
        s[1][nt] = MFMA16(qf[1][ss], kf, s[1][nt]);
      }
    }
    __builtin_amdgcn_s_setprio(0);

    if (tk0 + 63 > qbase) {
      #pragma unroll
      for (int mt = 0; mt < 2; ++mt)
        #pragma unroll
        for (int nt = 0; nt < 4; ++nt) {
          const int key = tk0 + nt*16 + l16;
          #pragma unroll
          for (int r = 0; r < 4; ++r) {
            const int qr = qbase + mt*16 + quad*4 + r;
            if (key > qr) s[mt][nt][r] = -1e30f;
          }
        }
    }

    #pragma unroll
    for (int mt = 0; mt < 2; ++mt) {
      #pragma unroll
      for (int r = 0; r < 4; ++r) {
        const float p0 = EXP2(s[mt][0][r]), p1 = EXP2(s[mt][1][r]);
        const float p2 = EXP2(s[mt][2][r]), p3 = EXP2(s[mt][3][r]);
        lrow[mt][r] += (p0 + p1) + (p2 + p3);
        const int q = mt*16 + quad*4 + r;
        const unsigned w0 = __builtin_amdgcn_perm(__float_as_uint(p1), __float_as_uint(p0), 0x07060302u);
        const unsigned w1 = __builtin_amdgcn_perm(__float_as_uint(p3), __float_as_uint(p2), 0x07060302u);
        pw32[q*32 + (((c0 + q)     & 7) << 2) + dwl] = w0;
        pw32[q*32 + (((c0 + q + 4) & 7) << 2) + dwl] = w1;
      }
    }

    __builtin_amdgcn_s_setprio(1);
    #pragma unroll
    for (int ss = 0; ss < 2; ++ss) {
      short8 pf0 = *(const short8*)&pw[l16*64      + ((4*ss + quad + l16) & 7)*8];
      short8 pf1 = *(const short8*)&pw[(16+l16)*64 + ((4*ss + quad + l16) & 7)*8];
      #pragma unroll
      for (int nd = 0; nd < 4; ++nd) {
        const int d = nd*16 + l16;
        short8 vf = *(const short8*)&vb[(d*8 + ((ss*4+quad) ^ x7))*8];
        o[0][nd] = MFMA16(pf0, vf, o[0][nd]);
        o[1][nd] = MFMA16(pf1, vf, o[1][nd]);
      }
    }
    __builtin_amdgcn_s_setprio(0);
  }

  #pragma unroll
  for (int mt = 0; mt < 2; ++mt) {
    #pragma unroll
    for (int r = 0; r < 4; ++r) {
      float lsum = lrow[mt][r];
      lsum += __shfl_xor(lsum, 1);
      lsum += __shfl_xor(lsum, 2);
      lsum += __shfl_xor(lsum, 4);
      lsum += __shfl_xor(lsum, 8);
      const float inv = 1.0f / lsum;
      const int tt = qbase + mt*16 + quad*4 + r;
      #pragma unroll
      for (int nd = 0; nd < 4; ++nd)
        att[(size_t)(b*T_ + tt) * C_ + h*64 + nd*16 + l16] =
            __float2bfloat16(o[mt][nd][r] * inv);
    }
  }
}

extern "C" void kernel_launch(void* const* d_in, const int* in_sizes, int n_in,
                              void* d_out, int out_size, void* d_ws, size_t ws_size,
                              hipStream_t stream) {
  const float* x     = (const float*)d_in[0];
  const float* Wqkv  = (const float*)d_in[1];
  const float* Wproj = (const float*)d_in[2];
  const float* bproj = (const float*)d_in[3];
  float* out = (float*)d_out;

  char* ws = (char*)d_ws;
  bf16* xb     = (bf16*)(ws + 0);          // 8192x1024       16,777,216 B
  bf16* wqkvT  = (bf16*)(ws + 16777216);   // 3072x1024        6,291,456 B
  bf16* wprojT = (bf16*)(ws + 23068672);   // 1024x1024        2,097,152 B
  bf16* Qb     = (bf16*)(ws + 25165824);   // [B,H,T,HS]      16,777,216 B
  bf16* Kb     = (bf16*)(ws + 41943040);   // [B,H,T,HS]      16,777,216 B
  bf16* Vt     = (bf16*)(ws + 58720256);   // [B,H,HS,T] perm 16,777,216 B
  bf16* att    = (bf16*)(ws + 75497472);   // [B,T,C]         16,777,216 B

  k_prep<<<dim3(5120), 256, 0, stream>>>(x, xb, Wqkv, wqkvT, Wproj, wprojT);
  k_gemm256<<<dim3(384), 512, 0, stream>>>(xb, wqkvT, Qb, Kb, Vt);
  k_attn<<<dim3(1024), 256, 0, stream>>>(Qb, Kb, Vt, att);
  k_gemm<1, 8><<<dim3(512), 256, 0, stream>>>(
      att, wprojT, C_, C_, nullptr, nullptr, nullptr, out, bproj);
}

// Round 5
// 225.542 us; speedup vs baseline: 1.0159x; 1.0159x over previous
//
#include <hip/hip_runtime.h>
#include <hip/hip_bf16.h>
#include <cstdint>
#include <cstddef>

using bf16 = __hip_bfloat16;
typedef __attribute__((ext_vector_type(8))) short short8;
typedef __attribute__((ext_vector_type(4))) float floatx4;

#define B_ 4
#define T_ 2048
#define C_ 1024
#define H_ 16
#define HS_ 64
#define BT_ (B_*T_)
#define N3C (3*C_)

#define MFMA16(a,b,c) __builtin_amdgcn_mfma_f32_16x16x32_bf16((a),(b),(c),0,0,0)

#if __has_builtin(__builtin_amdgcn_exp2f)
#define EXP2(x) __builtin_amdgcn_exp2f(x)
#else
#define EXP2(x) exp2f(x)
#endif

static __device__ __forceinline__ void gld16(const bf16* g, bf16* l) {
  __builtin_amdgcn_global_load_lds(
      (const __attribute__((address_space(1))) unsigned int*)g,
      (__attribute__((address_space(3))) unsigned int*)l, 16, 0, 0);
}

static __device__ __forceinline__ unsigned short f2bf_us(float x) {
  bf16 b = __float2bfloat16(x);
  return *(unsigned short*)&b;
}

// ---------------- fused prep: cast x + transpose-cast both weights ----------
__global__ __launch_bounds__(256)
void k_prep(const float* __restrict__ x, bf16* __restrict__ xb,
            const float* __restrict__ Wqkv, bf16* __restrict__ wqkvT,
            const float* __restrict__ Wproj, bf16* __restrict__ wprojT)
{
  const int bid = blockIdx.x, tid = threadIdx.x;
  __shared__ float tile[64][65];

  if (bid < 4096) {
    const int i = bid*256 + tid;
    const float4 v0 = ((const float4*)x)[2*i];
    const float4 v1 = ((const float4*)x)[2*i + 1];
    union { bf16 b[8]; uint4 u; } cvt;
    cvt.b[0] = __float2bfloat16(v0.x);
    cvt.b[1] = __float2bfloat16(v0.y);
    cvt.b[2] = __float2bfloat16(v0.z);
    cvt.b[3] = __float2bfloat16(v0.w);
    cvt.b[4] = __float2bfloat16(v1.x);
    cvt.b[5] = __float2bfloat16(v1.y);
    cvt.b[6] = __float2bfloat16(v1.z);
    cvt.b[7] = __float2bfloat16(v1.w);
    ((uint4*)xb)[i] = cvt.u;
    return;
  }

  const float* in; bf16* out; int N, n0, k0;
  if (bid < 4864) {
    const int j = bid - 4096;
    in = Wqkv; out = wqkvT; N = N3C;
    n0 = (j % 48) * 64; k0 = (j / 48) * 64;
  } else {
    const int j = bid - 4864;
    in = Wproj; out = wprojT; N = C_;
    n0 = (j % 16) * 64; k0 = (j / 16) * 64;
  }
  const int r = tid >> 6, c = tid & 63;
  #pragma unroll
  for (int j = 0; j < 16; ++j)
    tile[r + j*4][c] = in[(size_t)(k0 + r + j*4) * N + n0 + c];
  __syncthreads();
  #pragma unroll
  for (int j = 0; j < 16; ++j) {
    int rr = r + j*4;
    out[(size_t)(n0 + rr) * C_ + k0 + c] = __float2bfloat16(tile[c][rr]);
  }
}

// ---------------- QKV GEMM: 128x128, BK=64 drain-barrier (proven 64.5us) ----
// R14: reverted to the R1 winner after three deep-pipeline ports (BK32
// counted, 256^2 x2) all measured slower (70.3-75.7 vs 64.5). This 2-barrier
// structure at 2 blocks/CU with even grid rounds is the empirical optimum
// for this shape. MODE 0 epilogue: Q/K scatter (nb<16); V blocks (nb>=16)
// transpose via LDS to key-permuted Vt [B,H,HS,T].
template<int MODE, int NB>
__global__ __launch_bounds__(256, 2)
void k_gemm(const bf16* __restrict__ A, const bf16* __restrict__ Bt,
            int N, int K,
            bf16* __restrict__ Qb, bf16* __restrict__ Kb, bf16* __restrict__ Vt,
            float* __restrict__ Out, const float* __restrict__ bias)
{
  __shared__ __align__(16) char smem[65536];   // 2x16KB sA + 2x16KB sB; epilogue reuses
  bf16* const sAb = (bf16*)smem;               // [2][8192]
  bf16* const sBb = (bf16*)(smem + 32768);     // [2][8192]

  const int tid  = threadIdx.x;
  const int lane = tid & 63, wave = tid >> 6;
  const int quad = lane >> 4, l16 = lane & 15;
  const int wm = wave >> 1, wn = wave & 1;

  const int g = blockIdx.x;
  const int xcd = g & 7;
  const int local = g >> 3;
  const int nb = local % NB;
  const int mb = (local / NB) * 8 + xcd;
  const int m0 = mb * 128, n0 = nb * 128;

  // staging: thread t covers rows ra, ra+32, ra+64, ra+96; slot t holds
  // physical chunk (t&7) of its row = global chunk (t&7)^(ra&7).
  const int ra = tid >> 3;
  const int gc = (tid & 7) ^ (ra & 7);
  const bf16* aptr = A  + (size_t)(m0 + ra) * K + gc*8;
  const bf16* bptr = Bt + (size_t)(n0 + ra) * K + gc*8;
  const size_t rj = (size_t)32 * K;   // (ra+32)&7 == ra&7 -> same gc

  floatx4 acc[4][4] = {};
  const int KI = K >> 6;              // 16 staged tiles
  const int x7a = l16 & 7;

  for (int i = 0; i <= KI; ++i) {
    __syncthreads();
    if (i < KI) {
      const int k0 = i << 6;
      bf16* sa = sAb + (i & 1) * 8192;
      bf16* sb = sBb + (i & 1) * 8192;
      #pragma unroll
      for (int q2 = 0; q2 < 4; ++q2) {
        gld16(aptr + q2*rj + k0, sa + q2*2048 + tid*8);
        gld16(bptr + q2*rj + k0, sb + q2*2048 + tid*8);
      }
    }
    if (i == 0) continue;
    const bf16* sa = sAb + ((i-1) & 1) * 8192;
    const bf16* sb = sBb + ((i-1) & 1) * 8192;
    #pragma unroll
    for (int ks = 0; ks < 2; ++ks) {
      short8 af[4], bfm[4];
      #pragma unroll
      for (int ii = 0; ii < 4; ++ii)
        af[ii] = *(const short8*)&sa[(wm*64 + ii*16 + l16)*64 + ((ks*4 + quad) ^ x7a)*8];
      #pragma unroll
      for (int ii = 0; ii < 4; ++ii)
        bfm[ii] = *(const short8*)&sb[(wn*64 + ii*16 + l16)*64 + ((ks*4 + quad) ^ x7a)*8];
      #pragma unroll
      for (int ii = 0; ii < 4; ++ii)
        #pragma unroll
        for (int j = 0; j < 4; ++j)
          acc[ii][j] = MFMA16(af[ii], bfm[j], acc[ii][j]);
    }
  }

  if (MODE == 0 && nb >= 16) {
    // ---- V block: LDS transpose -> coalesced, key-permuted Vt stores ----
    __syncthreads();                      // all waves done with sA/sB
    unsigned short* epi = (unsigned short*)smem;   // [128 cc][132 pad]
    #pragma unroll
    for (int i = 0; i < 4; ++i) {
      const int tl = wm*64 + i*16 + quad*4;
      #pragma unroll
      for (int j = 0; j < 4; ++j) {
        const int ccl = wn*64 + j*16 + l16;
        #pragma unroll
        for (int r = 0; r < 4; ++r)
          epi[ccl*132 + tl + r] = f2bf_us(acc[i][j][r]);
      }
    }
    __syncthreads();
    const int b  = m0 >> 11;
    const int t0 = m0 & 2047;            // token offset within this sequence
    const int h0 = (n0 - 2*C_) >> 6;
    #pragma unroll
    for (int it = 0; it < 32; ++it) {
      const int id = it*256 + tid;
      const int tp = id & 31;
      const int rest = id >> 5;
      const int tl64 = (rest & 1) * 64;
      const int ccl = rest >> 1;
      const int k0p = tp + (tp & 16);     // keys (k0p, k0p+16) -> positions (2tp, 2tp+1)
      const unsigned lo = epi[ccl*132 + tl64 + k0p];
      const unsigned hi = epi[ccl*132 + tl64 + k0p + 16];
      const int h = h0 + (ccl >> 6), d = ccl & 63;
      unsigned* row = (unsigned*)(Vt + ((size_t)(b*H_ + h) * HS_ + d) * T_);
      row[(t0 >> 1) + tl64/2 + tp] = lo | (hi << 16);
    }
  } else {
    #pragma unroll
    for (int i = 0; i < 4; ++i) {
      const int rowb = m0 + wm*64 + i*16 + quad*4;
      #pragma unroll
      for (int j = 0; j < 4; ++j) {
        const int col = n0 + wn*64 + j*16 + l16;
        #pragma unroll
        for (int r = 0; r < 4; ++r) {
          const float v = acc[i][j][r];
          const int rr = rowb + r;
          if (MODE == 0) {
            const int b = rr >> 11, t = rr & 2047;
            const int h = (col >> 6) & 15, d = col & 63;
            const size_t addr = (((size_t)(b*H_ + h) * T_ + t) << 6) + d;
            if (nb < 8) {
              // fold 1/sqrt(64) * log2(e) so attention softmax can use exp2
              Qb[addr] = __float2bfloat16(v * 0.18033688f);
            } else {
              Kb[addr] = __float2bfloat16(v);
            }
          } else {
            Out[(size_t)rr * N + col] = v + bias[col];
          }
        }
      }
    }
  }
}

// ---------------- proj GEMM: 128x128, BK=32, 4-deep counted-vmcnt -----------
// R14: kept from R3 where it measured faster than BK=64 drain for the short
// K=1024 proj (R3 vs R4 delta isolates this kernel). 0 bank conflicts
// (verified swizzle: phys chunk = c^((r>>1)&3), bank-quad = 4*(r&1)+(c^swz)).
// Pipeline: stage tile i+3 while computing tile i; vmcnt(8) at tile top
// retires tile i block-wide while i+1/i+2 stay in flight; never drains.
template<int NB>
__global__ __launch_bounds__(256, 2)
void k_proj(const bf16* __restrict__ A, const bf16* __restrict__ Bt,
            int N, int K, float* __restrict__ Out, const float* __restrict__ bias)
{
  __shared__ __align__(16) char smem[65536];
  bf16* const sA = (bf16*)smem;               // [4][4096]  128 rows x 32
  bf16* const sB = (bf16*)(smem + 32768);     // [4][4096]

  const int tid  = threadIdx.x;
  const int lane = tid & 63, wave = tid >> 6;
  const int quad = lane >> 4, l16 = lane & 15;
  const int wm = wave >> 1, wn = wave & 1;

  const int g = blockIdx.x;
  const int xcd = g & 7;
  const int local = g >> 3;
  const int nb = local % NB;
  const int mb = (local / NB) * 8 + xcd;
  const int m0 = mb * 128, n0 = nb * 128;

  const int ra = tid >> 2;
  const int gc = (tid & 3) ^ ((ra >> 1) & 3);
  const bf16* aptr = A  + (size_t)(m0 + ra) * K + gc*8;
  const bf16* bptr = Bt + (size_t)(n0 + ra) * K + gc*8;
  const size_t rj = (size_t)64 * K;

  const int KT = K >> 5;                      // 32 K-tiles
  floatx4 acc[4][4] = {};
  const int swz = (l16 >> 1) & 3;
  const int aoff = (wm*64 + l16)*32 + (quad ^ swz)*8;
  const int boff = (wn*64 + l16)*32 + (quad ^ swz)*8;

  // prologue: stage tiles 0..2 (12 loads in flight)
  #pragma unroll
  for (int t = 0; t < 3; ++t) {
    bf16* sa = sA + t*4096; bf16* sb = sB + t*4096;
    gld16(aptr + t*32,      sa + tid*8);
    gld16(aptr + rj + t*32, sa + 2048 + tid*8);
    gld16(bptr + t*32,      sb + tid*8);
    gld16(bptr + rj + t*32, sb + 2048 + tid*8);
  }

  #pragma unroll 1
  for (int i = 0; i < KT; ++i) {
    if (i < KT-2)       asm volatile("s_waitcnt vmcnt(8)" ::: "memory");
    else if (i == KT-2) asm volatile("s_waitcnt vmcnt(4)" ::: "memory");
    else                asm volatile("s_waitcnt vmcnt(0)" ::: "memory");
    asm volatile("s_barrier" ::: "memory");
    if (i < KT-3) {
      const int t = i + 3;
      bf16* sa = sA + (t & 3)*4096; bf16* sb = sB + (t & 3)*4096;
      gld16(aptr + t*32,      sa + tid*8);
      gld16(aptr + rj + t*32, sa + 2048 + tid*8);
      gld16(bptr + t*32,      sb + tid*8);
      gld16(bptr + rj + t*32, sb + 2048 + tid*8);
    }
    const bf16* sa = sA + (i & 3)*4096;
    const bf16* sb = sB + (i & 3)*4096;
    short8 af[4], bfm[4];
    #pragma unroll
    for (int ii = 0; ii < 4; ++ii) af[ii]  = *(const short8*)&sa[aoff + ii*512];
    #pragma unroll
    for (int j = 0; j < 4; ++j)    bfm[j]  = *(const short8*)&sb[boff + j*512];
    __builtin_amdgcn_s_setprio(1);
    #pragma unroll
    for (int ii = 0; ii < 4; ++ii)
      #pragma unroll
      for (int j = 0; j < 4; ++j)
        acc[ii][j] = MFMA16(af[ii], bfm[j], acc[ii][j]);
    __builtin_amdgcn_s_setprio(0);
  }

  #pragma unroll
  for (int i = 0; i < 4; ++i) {
    const int rowb = m0 + wm*64 + i*16 + quad*4;
    #pragma unroll
    for (int j = 0; j < 4; ++j) {
      const int col = n0 + wn*64 + j*16 + l16;
      #pragma unroll
      for (int r = 0; r < 4; ++r)
        Out[(size_t)(rowb + r) * N + col] = acc[i][j][r] + bias[col];
    }
  }
}

// ---------------- flash attention (causal) ----------------------------------
__global__ __launch_bounds__(256, 3)
void k_attn(const bf16* __restrict__ Q, const bf16* __restrict__ K,
            const bf16* __restrict__ Vt, bf16* __restrict__ att)
{
  __shared__ bf16 kbuf[2][64*64];   // [buf][key][dc^key&7]
  __shared__ bf16 vbuf[2][64*64];   // [buf][d][pc^d&7]  (positions, permuted)
  __shared__ bf16 pbuf[4][32*64];   // per-wave [q][(pc+q)&7 rotation]

  const int tid  = threadIdx.x;
  const int lane = tid & 63, wave = tid >> 6;
  const int quad = lane >> 4, l16 = lane & 15;
  const int x7 = l16 & 7;

  const int g  = blockIdx.x;              // 1024 blocks
  const int bh = (g & 7) * 8 + ((g >> 3) & 7);  // 16 blocks of a bh share XCD g&7
  const int qt = 15 - (g >> 6);           // q-tile index; heavy (qt=15) first
  const int b = bh >> 4, h = bh & 15;

  const bf16* Qp = Q  + (size_t)bh * T_ * HS_;
  const bf16* Kp = K  + (size_t)bh * T_ * HS_;
  const bf16* Vp = Vt + (size_t)bh * HS_ * T_;

  const int qbase = qt*128 + wave*32;
  const int ntk = 2*qt + 2;               // key tiles to process

  short8 qf[2][2];
  #pragma unroll
  for (int mt = 0; mt < 2; ++mt)
    #pragma unroll
    for (int ss = 0; ss < 2; ++ss)
      qf[mt][ss] = *(const short8*)(Qp + (size_t)(qbase + mt*16 + l16) * HS_ + ss*32 + quad*8);

  floatx4 o[2][4] = {};
  float lrow[2][4] = {};

  const bf16* kg[2]; const bf16* vg[2];
  int ldsoff[2];
  #pragma unroll
  for (int it = 0; it < 2; ++it) {
    const int c = it*256 + tid;
    const int row = c >> 3;
    const int col = (c & 7) ^ (row & 7);
    kg[it] = Kp + (size_t)row * HS_ + col*8;
    vg[it] = Vp + (size_t)row * T_ + col*8;
    ldsoff[it] = c*8;
  }

  bf16* pw = pbuf[wave];
  unsigned int* pw32 = (unsigned int*)pw;
  const int c0 = l16 >> 2;
  const int dwl = l16 & 3;

  for (int i = 0; i <= ntk; ++i) {
    __syncthreads();
    if (i < ntk) {
      const int stk0 = i * 64;
      bf16* kb = kbuf[i & 1];
      bf16* vb = vbuf[i & 1];
      #pragma unroll
      for (int it = 0; it < 2; ++it) {
        gld16(kg[it] + (size_t)stk0 * HS_, kb + ldsoff[it]);
        gld16(vg[it] + stk0,               vb + ldsoff[it]);
      }
    }
    if (i == 0) continue;
    const int tk  = i - 1;
    const int tk0 = tk * 64;
    if (tk0 > qbase + 31) continue;
    const bf16* kb = kbuf[tk & 1];
    const bf16* vb = vbuf[tk & 1];

    floatx4 s[2][4] = {};
    __builtin_amdgcn_s_setprio(1);
    #pragma unroll
    for (int nt = 0; nt < 4; ++nt) {
      const int key = nt*16 + l16;
      #pragma unroll
      for (int ss = 0; ss < 2; ++ss) {
        short8 kf = *(const short8*)&kb[(key*8 + ((ss*4+quad) ^ x7))*8];
        s[0][nt] = MFMA16(qf[0][ss], kf, s[0][nt]);
        s[1][nt] = MFMA16(qf[1][ss], kf, s[1][nt]);
      }
    }
    __builtin_amdgcn_s_setprio(0);

    if (tk0 + 63 > qbase) {
      #pragma unroll
      for (int mt = 0; mt < 2; ++mt)
        #pragma unroll
        for (int nt = 0; nt < 4; ++nt) {
          const int key = tk0 + nt*16 + l16;
          #pragma unroll
          for (int r = 0; r < 4; ++r) {
            const int qr = qbase + mt*16 + quad*4 + r;
            if (key > qr) s[mt][nt][r] = -1e30f;
          }
        }
    }

    #pragma unroll
    for (int mt = 0; mt < 2; ++mt) {
      #pragma unroll
      for (int r = 0; r < 4; ++r) {
        const float p0 = EXP2(s[mt][0][r]), p1 = EXP2(s[mt][1][r]);
        const float p2 = EXP2(s[mt][2][r]), p3 = EXP2(s[mt][3][r]);
        lrow[mt][r] += (p0 + p1) + (p2 + p3);
        const int q = mt*16 + quad*4 + r;
        const unsigned w0 = __builtin_amdgcn_perm(__float_as_uint(p1), __float_as_uint(p0), 0x07060302u);
        const unsigned w1 = __builtin_amdgcn_perm(__float_as_uint(p3), __float_as_uint(p2), 0x07060302u);
        pw32[q*32 + (((c0 + q)     & 7) << 2) + dwl] = w0;
        pw32[q*32 + (((c0 + q + 4) & 7) << 2) + dwl] = w1;
      }
    }

    __builtin_amdgcn_s_setprio(1);
    #pragma unroll
    for (int ss = 0; ss < 2; ++ss) {
      short8 pf0 = *(const short8*)&pw[l16*64      + ((4*ss + quad + l16) & 7)*8];
      short8 pf1 = *(const short8*)&pw[(16+l16)*64 + ((4*ss + quad + l16) & 7)*8];
      #pragma unroll
      for (int nd = 0; nd < 4; ++nd) {
        const int d = nd*16 + l16;
        short8 vf = *(const short8*)&vb[(d*8 + ((ss*4+quad) ^ x7))*8];
        o[0][nd] = MFMA16(pf0, vf, o[0][nd]);
        o[1][nd] = MFMA16(pf1, vf, o[1][nd]);
      }
    }
    __builtin_amdgcn_s_setprio(0);
  }

  #pragma unroll
  for (int mt = 0; mt < 2; ++mt) {
    #pragma unroll
    for (int r = 0; r < 4; ++r) {
      float lsum = lrow[mt][r];
      lsum += __shfl_xor(lsum, 1);
      lsum += __shfl_xor(lsum, 2);
      lsum += __shfl_xor(lsum, 4);
      lsum += __shfl_xor(lsum, 8);
      const float inv = 1.0f / lsum;
      const int tt = qbase + mt*16 + quad*4 + r;
      #pragma unroll
      for (int nd = 0; nd < 4; ++nd)
        att[(size_t)(b*T_ + tt) * C_ + h*64 + nd*16 + l16] =
            __float2bfloat16(o[mt][nd][r] * inv);
    }
  }
}

extern "C" void kernel_launch(void* const* d_in, const int* in_sizes, int n_in,
                              void* d_out, int out_size, void* d_ws, size_t ws_size,
                              hipStream_t stream) {
  const float* x     = (const float*)d_in[0];
  const float* Wqkv  = (const float*)d_in[1];
  const float* Wproj = (const float*)d_in[2];
  const float* bproj = (const float*)d_in[3];
  float* out = (float*)d_out;

  char* ws = (char*)d_ws;
  bf16* xb     = (bf16*)(ws + 0);          // 8192x1024       16,777,216 B
  bf16* wqkvT  = (bf16*)(ws + 16777216);   // 3072x1024        6,291,456 B
  bf16* wprojT = (bf16*)(ws + 23068672);   // 1024x1024        2,097,152 B
  bf16* Qb     = (bf16*)(ws + 25165824);   // [B,H,T,HS]      16,777,216 B
  bf16* Kb     = (bf16*)(ws + 41943040);   // [B,H,T,HS]      16,777,216 B
  bf16* Vt     = (bf16*)(ws + 58720256);   // [B,H,HS,T] perm 16,777,216 B
  bf16* att    = (bf16*)(ws + 75497472);   // [B,T,C]         16,777,216 B

  k_prep<<<dim3(5120), 256, 0, stream>>>(x, xb, Wqkv, wqkvT, Wproj, wprojT);
  k_gemm<0, 24><<<dim3(1536), 256, 0, stream>>>(
      xb, wqkvT, N3C, C_, Qb, Kb, Vt, nullptr, nullptr);
  k_attn<<<dim3(1024), 256, 0, stream>>>(Qb, Kb, Vt, att);
  k_proj<8><<<dim3(512), 256, 0, stream>>>(
      att, wprojT, C_, C_, out, bproj);
}

// Round 6
// 217.609 us; speedup vs baseline: 1.0529x; 1.0365x over previous
//
#include <hip/hip_runtime.h>
#include <hip/hip_bf16.h>
#include <cstdint>
#include <cstddef>

using bf16 = __hip_bfloat16;
typedef __attribute__((ext_vector_type(8))) short short8;
typedef __attribute__((ext_vector_type(4))) float floatx4;

#define B_ 4
#define T_ 2048
#define C_ 1024
#define H_ 16
#define HS_ 64
#define BT_ (B_*T_)
#define N3C (3*C_)

#define MFMA16(a,b,c) __builtin_amdgcn_mfma_f32_16x16x32_bf16((a),(b),(c),0,0,0)

#if __has_builtin(__builtin_amdgcn_exp2f)
#define EXP2(x) __builtin_amdgcn_exp2f(x)
#else
#define EXP2(x) exp2f(x)
#endif

static __device__ __forceinline__ void gld16(const bf16* g, bf16* l) {
  __builtin_amdgcn_global_load_lds(
      (const __attribute__((address_space(1))) unsigned int*)g,
      (__attribute__((address_space(3))) unsigned int*)l, 16, 0, 0);
}

static __device__ __forceinline__ unsigned short f2bf_us(float x) {
  bf16 b = __float2bfloat16(x);
  return *(unsigned short*)&b;
}

// ---------------- fused prep: cast x + transpose-cast both weights ----------
__global__ __launch_bounds__(256)
void k_prep(const float* __restrict__ x, bf16* __restrict__ xb,
            const float* __restrict__ Wqkv, bf16* __restrict__ wqkvT,
            const float* __restrict__ Wproj, bf16* __restrict__ wprojT)
{
  const int bid = blockIdx.x, tid = threadIdx.x;
  __shared__ float tile[64][65];

  if (bid < 4096) {
    const int i = bid*256 + tid;
    const float4 v0 = ((const float4*)x)[2*i];
    const float4 v1 = ((const float4*)x)[2*i + 1];
    union { bf16 b[8]; uint4 u; } cvt;
    cvt.b[0] = __float2bfloat16(v0.x);
    cvt.b[1] = __float2bfloat16(v0.y);
    cvt.b[2] = __float2bfloat16(v0.z);
    cvt.b[3] = __float2bfloat16(v0.w);
    cvt.b[4] = __float2bfloat16(v1.x);
    cvt.b[5] = __float2bfloat16(v1.y);
    cvt.b[6] = __float2bfloat16(v1.z);
    cvt.b[7] = __float2bfloat16(v1.w);
    ((uint4*)xb)[i] = cvt.u;
    return;
  }

  const float* in; bf16* out; int N, n0, k0;
  if (bid < 4864) {
    const int j = bid - 4096;
    in = Wqkv; out = wqkvT; N = N3C;
    n0 = (j % 48) * 64; k0 = (j / 48) * 64;
  } else {
    const int j = bid - 4864;
    in = Wproj; out = wprojT; N = C_;
    n0 = (j % 16) * 64; k0 = (j / 16) * 64;
  }
  const int r = tid >> 6, c = tid & 63;
  #pragma unroll
  for (int j = 0; j < 16; ++j)
    tile[r + j*4][c] = in[(size_t)(k0 + r + j*4) * N + n0 + c];
  __syncthreads();
  #pragma unroll
  for (int j = 0; j < 16; ++j) {
    int rr = r + j*4;
    out[(size_t)(n0 + rr) * C_ + k0 + c] = __float2bfloat16(tile[c][rr]);
  }
}

// ---------------- QKV GEMM: 256x384, BK=32, 3-buf, template-phase pipeline --
// R15: tail-free deep pipeline.
//  - Grid 256 = one block per CU exactly (zero dispatch-round tail; R4's
//    384-block 1.5-round layout wasted 25%).
//  - BN=384 as three 128-col groups {Q,K,V} of head-slice nb (B-LDS rows
//    0-127=Q, 128-255=K, 256-383=V) so no tile straddles the Q/K/V boundary.
//  - 8 waves 2Mx4N, per-wave 128x96, acc[8][6]. LDS traffic per K-32 tile =
//    112KB vs 480 MFMA-cy/SIMD -> 93% LDS-ratio ceiling (128^2/BK64 = 62%,
//    which bounded every prior version at ~36%). B-frags register-held
//    across both phases (re-reading would tip LDS-bound).
//  - 3 K-32 bufs (120KB LDS): stage tile i+2 while computing i. One counted
//    vmcnt(5) gate per tile (tail: 0). Template phase discipline:
//    {ds_read subtile; issue stage; s_barrier; lgkmcnt(0); sched_barrier;
//     setprio(1); 24 MFMA; setprio(0); s_barrier}  (m196: the fine
//    interleave is the lever; coarse split hurts).
//  - Hazards: RAW = vmcnt(5)+barrier one tile ahead of reads. WAR =
//    buf[(i+2)%3] last read in tile i-1, lgkm-retired before the barrier
//    every wave passed before the stage issues.
//  - K ascending, one MFMA per K-32 -> accumulation order identical to R5.
// Epilogue: Q (pre-scaled) / K scatter; V = block-wide LDS transpose into
// key-permuted Vt [B,H,HS,T] (same pairing as R5).
__global__ __launch_bounds__(512, 1)
void k_gemmqkv(const bf16* __restrict__ A, const bf16* __restrict__ Bt,
               bf16* __restrict__ Qb, bf16* __restrict__ Kb, bf16* __restrict__ Vt)
{
  __shared__ __align__(16) char smem[122880];
  bf16* const sA = (bf16*)smem;                 // [3][8192]  256 rows x 32
  bf16* const sB = (bf16*)(smem + 49152);       // [3][12288] 384 rows x 32

  const int tid  = threadIdx.x;
  const int lane = tid & 63, wave = tid >> 6;
  const int quad = lane >> 4, l16 = lane & 15;
  const int wm = wave >> 2, wn = wave & 3;      // 2M x 4N

  const int g = blockIdx.x;                     // 256 blocks
  const int xcd = g & 7;
  const int local = g >> 3;                     // 0..31
  const int nb = local & 7;
  const int mb = (local >> 3) * 8 + xcd;        // 0..31
  const int m0 = mb * 256;
  const int n0q = nb * 128;

  // staging: thread t -> row t>>2 of a 128-row pass, phys chunk t&3 holds
  // global chunk (t&3)^((row>>1)&3); all pass bases are 128-row aligned so
  // the swizzle phase is identical across passes.
  const int ra = tid >> 2;
  const int gc = (tid & 3) ^ ((ra >> 1) & 3);
  const bf16* aptr = A  + (size_t)(m0 + ra) * C_ + gc*8;
  const bf16* bp0  = Bt + (size_t)(n0q + ra) * C_ + gc*8;          // Q group
  const bf16* bp1  = Bt + (size_t)(1024 + n0q + ra) * C_ + gc*8;   // K group
  const bf16* bp2  = Bt + (size_t)(2048 + n0q + ra) * C_ + gc*8;   // V group

  floatx4 acc[8][6] = {};
  const int swz = (l16 >> 1) & 3;
  const int aoff = (wm*128 + l16)*32 + (quad ^ swz)*8;
  const int boff = (wn*96  + l16)*32 + (quad ^ swz)*8;

#define STAGE_A(t,s) { bf16* d = sA + (s)*8192;                     \
    gld16(aptr + (t)*32,                  d + tid*8);               \
    gld16(aptr + (size_t)128*C_ + (t)*32, d + 4096 + tid*8); }
#define STAGE_B(t,s) { bf16* d = sB + (s)*12288;                    \
    gld16(bp0 + (t)*32, d + tid*8);                                 \
    gld16(bp1 + (t)*32, d + 4096 + tid*8);                          \
    gld16(bp2 + (t)*32, d + 8192 + tid*8); }

  // prologue: tiles 0,1 staged (10 loads); gate tile 0 (5 younger remain)
  STAGE_A(0,0); STAGE_B(0,0);
  STAGE_A(1,1); STAGE_B(1,1);
  asm volatile("s_waitcnt vmcnt(5)" ::: "memory");
  asm volatile("s_barrier" ::: "memory");

  int cs = 0;                                   // i % 3
  #pragma unroll 1
  for (int i = 0; i < 32; ++i) {
    const int s2 = (cs >= 1) ? cs - 1 : 2;      // (i+2) % 3
    const bf16* sa = sA + cs*8192;
    const bf16* sb = sB + cs*12288;
    short8 bq[6], af[4];
    // ---- phase 0: read B(6)+A(4), issue A-stage, barrier, 24 MFMA ----
    #pragma unroll
    for (int j = 0; j < 6; ++j)    bq[j]  = *(const short8*)&sb[boff + j*512];
    #pragma unroll
    for (int ii = 0; ii < 4; ++ii) af[ii] = *(const short8*)&sa[aoff + ii*512];
    if (i < 30) STAGE_A(i+2, s2);
    asm volatile("s_barrier" ::: "memory");
    asm volatile("s_waitcnt lgkmcnt(0)" ::: "memory");
    __builtin_amdgcn_sched_barrier(0);
    __builtin_amdgcn_s_setprio(1);
    #pragma unroll
    for (int ii = 0; ii < 4; ++ii)
      #pragma unroll
      for (int j = 0; j < 6; ++j)
        acc[ii][j] = MFMA16(af[ii], bq[j], acc[ii][j]);
    __builtin_amdgcn_s_setprio(0);
    asm volatile("s_barrier" ::: "memory");
    // ---- phase 1: read A(4), issue B-stage, vmcnt gate, barrier, 24 MFMA --
    #pragma unroll
    for (int ii = 0; ii < 4; ++ii) af[ii] = *(const short8*)&sa[aoff + (4+ii)*512];
    if (i < 30) {
      STAGE_B(i+2, s2);
      asm volatile("s_waitcnt vmcnt(5)" ::: "memory");   // tile i+1 retired
    } else if (i == 30) {
      asm volatile("s_waitcnt vmcnt(0)" ::: "memory");   // tile 31 retired
    }
    asm volatile("s_barrier" ::: "memory");
    asm volatile("s_waitcnt lgkmcnt(0)" ::: "memory");
    __builtin_amdgcn_sched_barrier(0);
    __builtin_amdgcn_s_setprio(1);
    #pragma unroll
    for (int ii = 0; ii < 4; ++ii)
      #pragma unroll
      for (int j = 0; j < 6; ++j)
        acc[4+ii][j] = MFMA16(af[ii], bq[j], acc[4+ii][j]);
    __builtin_amdgcn_s_setprio(0);
    asm volatile("s_barrier" ::: "memory");
    cs = (cs == 2) ? 0 : cs + 1;
  }
#undef STAGE_A
#undef STAGE_B

  // ---- Q/K scatter (local cols 0-255) ----
  #pragma unroll
  for (int ii = 0; ii < 8; ++ii) {
    const int rowb = m0 + wm*128 + ii*16 + quad*4;
    #pragma unroll
    for (int j = 0; j < 6; ++j) {
      const int L = wn*96 + j*16 + l16;          // 16-aligned span: uniform side
      if (L < 256) {
        const int gcol = (L < 128) ? (n0q + L) : (1024 + n0q + L - 128);
        const int h = (gcol >> 6) & 15, d = gcol & 63;
        #pragma unroll
        for (int r = 0; r < 4; ++r) {
          const int rr = rowb + r;
          const int b = rr >> 11, t = rr & 2047;
          const size_t addr = (((size_t)(b*H_ + h) * T_ + t) << 6) + d;
          if (L < 128) Qb[addr] = __float2bfloat16(acc[ii][j][r] * 0.18033688f);
          else         Kb[addr] = __float2bfloat16(acc[ii][j][r]);
        }
      }
    }
  }

  // ---- V (local cols 256-383): LDS transpose -> key-permuted Vt ----
  // loop's final barrier already fenced all sA/sB readers.
  unsigned short* epi = (unsigned short*)smem;   // [128 cc][258 tl-pad]
  #pragma unroll
  for (int ii = 0; ii < 8; ++ii) {
    const int tl = wm*128 + ii*16 + quad*4;
    #pragma unroll
    for (int j = 0; j < 6; ++j) {
      const int L = wn*96 + j*16 + l16;
      if (L >= 256) {
        const int ccl = L - 256;                 // 0..127
        #pragma unroll
        for (int r = 0; r < 4; ++r)
          epi[ccl*258 + tl + r] = f2bf_us(acc[ii][j][r]);
      }
    }
  }
  __syncthreads();
  const int b  = m0 >> 11;
  const int t0 = m0 & 2047;
  #pragma unroll
  for (int it = 0; it < 32; ++it) {
    const int id = it*512 + tid;                 // 16384 dword-pairs
    const int tp = id & 31;
    const int rest = id >> 5;                    // 0..511
    const int tl64 = (rest & 3) * 64;            // 64-token group of 256 rows
    const int ccl = rest >> 2;                   // 0..127
    const int k0p = tp + (tp & 16);              // keys (k0p,k0p+16)->(2tp,2tp+1)
    const unsigned lo = epi[ccl*258 + tl64 + k0p];
    const unsigned hi = epi[ccl*258 + tl64 + k0p + 16];
    const int h = nb*2 + (ccl >> 6), d = ccl & 63;
    unsigned* row = (unsigned*)(Vt + ((size_t)(b*H_ + h) * HS_ + d) * T_);
    row[(t0 >> 1) + tl64/2 + tp] = lo | (hi << 16);
  }
}

// ---------------- proj GEMM: 128x128, BK=32, 4-deep counted-vmcnt -----------
template<int NB>
__global__ __launch_bounds__(256, 2)
void k_proj(const bf16* __restrict__ A, const bf16* __restrict__ Bt,
            int N, int K, float* __restrict__ Out, const float* __restrict__ bias)
{
  __shared__ __align__(16) char smem[65536];
  bf16* const sA = (bf16*)smem;               // [4][4096]  128 rows x 32
  bf16* const sB = (bf16*)(smem + 32768);     // [4][4096]

  const int tid  = threadIdx.x;
  const int lane = tid & 63, wave = tid >> 6;
  const int quad = lane >> 4, l16 = lane & 15;
  const int wm = wave >> 1, wn = wave & 1;

  const int g = blockIdx.x;
  const int xcd = g & 7;
  const int local = g >> 3;
  const int nb = local % NB;
  const int mb = (local / NB) * 8 + xcd;
  const int m0 = mb * 128, n0 = nb * 128;

  const int ra = tid >> 2;
  const int gc = (tid & 3) ^ ((ra >> 1) & 3);
  const bf16* aptr = A  + (size_t)(m0 + ra) * K + gc*8;
  const bf16* bptr = Bt + (size_t)(n0 + ra) * K + gc*8;
  const size_t rj = (size_t)64 * K;

  const int KT = K >> 5;                      // 32 K-tiles
  floatx4 acc[4][4] = {};
  const int swz = (l16 >> 1) & 3;
  const int aoff = (wm*64 + l16)*32 + (quad ^ swz)*8;
  const int boff = (wn*64 + l16)*32 + (quad ^ swz)*8;

  #pragma unroll
  for (int t = 0; t < 3; ++t) {
    bf16* sa = sA + t*4096; bf16* sb = sB + t*4096;
    gld16(aptr + t*32,      sa + tid*8);
    gld16(aptr + rj + t*32, sa + 2048 + tid*8);
    gld16(bptr + t*32,      sb + tid*8);
    gld16(bptr + rj + t*32, sb + 2048 + tid*8);
  }

  #pragma unroll 1
  for (int i = 0; i < KT; ++i) {
    if (i < KT-2)       asm volatile("s_waitcnt vmcnt(8)" ::: "memory");
    else if (i == KT-2) asm volatile("s_waitcnt vmcnt(4)" ::: "memory");
    else                asm volatile("s_waitcnt vmcnt(0)" ::: "memory");
    asm volatile("s_barrier" ::: "memory");
    if (i < KT-3) {
      const int t = i + 3;
      bf16* sa = sA + (t & 3)*4096; bf16* sb = sB + (t & 3)*4096;
      gld16(aptr + t*32,      sa + tid*8);
      gld16(aptr + rj + t*32, sa + 2048 + tid*8);
      gld16(bptr + t*32,      sb + tid*8);
      gld16(bptr + rj + t*32, sb + 2048 + tid*8);
    }
    const bf16* sa = sA + (i & 3)*4096;
    const bf16* sb = sB + (i & 3)*4096;
    short8 af[4], bfm[4];
    #pragma unroll
    for (int ii = 0; ii < 4; ++ii) af[ii]  = *(const short8*)&sa[aoff + ii*512];
    #pragma unroll
    for (int j = 0; j < 4; ++j)    bfm[j]  = *(const short8*)&sb[boff + j*512];
    __builtin_amdgcn_s_setprio(1);
    #pragma unroll
    for (int ii = 0; ii < 4; ++ii)
      #pragma unroll
      for (int j = 0; j < 4; ++j)
        acc[ii][j] = MFMA16(af[ii], bfm[j], acc[ii][j]);
    __builtin_amdgcn_s_setprio(0);
  }

  #pragma unroll
  for (int i = 0; i < 4; ++i) {
    const int rowb = m0 + wm*64 + i*16 + quad*4;
    #pragma unroll
    for (int j = 0; j < 4; ++j) {
      const int col = n0 + wn*64 + j*16 + l16;
      #pragma unroll
      for (int r = 0; r < 4; ++r)
        Out[(size_t)(rowb + r) * N + col] = acc[i][j][r] + bias[col];
    }
  }
}

// ---------------- flash attention (causal) ----------------------------------
__global__ __launch_bounds__(256, 3)
void k_attn(const bf16* __restrict__ Q, const bf16* __restrict__ K,
            const bf16* __restrict__ Vt, bf16* __restrict__ att)
{
  __shared__ bf16 kbuf[2][64*64];   // [buf][key][dc^key&7]
  __shared__ bf16 vbuf[2][64*64];   // [buf][d][pc^d&7]  (positions, permuted)
  __shared__ bf16 pbuf[4][32*64];   // per-wave [q][(pc+q)&7 rotation]

  const int tid  = threadIdx.x;
  const int lane = tid & 63, wave = tid >> 6;
  const int quad = lane >> 4, l16 = lane & 15;
  const int x7 = l16 & 7;

  const int g  = blockIdx.x;              // 1024 blocks
  const int bh = (g & 7) * 8 + ((g >> 3) & 7);  // 16 blocks of a bh share XCD g&7
  const int qt = 15 - (g >> 6);           // q-tile index; heavy (qt=15) first
  const int b = bh >> 4, h = bh & 15;

  const bf16* Qp = Q  + (size_t)bh * T_ * HS_;
  const bf16* Kp = K  + (size_t)bh * T_ * HS_;
  const bf16* Vp = Vt + (size_t)bh * HS_ * T_;

  const int qbase = qt*128 + wave*32;
  const int ntk = 2*qt + 2;               // key tiles to process

  short8 qf[2][2];
  #pragma unroll
  for (int mt = 0; mt < 2; ++mt)
    #pragma unroll
    for (int ss = 0; ss < 2; ++ss)
      qf[mt][ss] = *(const short8*)(Qp + (size_t)(qbase + mt*16 + l16) * HS_ + ss*32 + quad*8);

  floatx4 o[2][4] = {};
  float lrow[2][4] = {};

  const bf16* kg[2]; const bf16* vg[2];
  int ldsoff[2];
  #pragma unroll
  for (int it = 0; it < 2; ++it) {
    const int c = it*256 + tid;
    const int row = c >> 3;
    const int col = (c & 7) ^ (row & 7);
    kg[it] = Kp + (size_t)row * HS_ + col*8;
    vg[it] = Vp + (size_t)row * T_ + col*8;
    ldsoff[it] = c*8;
  }

  bf16* pw = pbuf[wave];
  unsigned int* pw32 = (unsigned int*)pw;
  const int c0 = l16 >> 2;
  const int dwl = l16 & 3;

  for (int i = 0; i <= ntk; ++i) {
    __syncthreads();
    if (i < ntk) {
      const int stk0 = i * 64;
      bf16* kb = kbuf[i & 1];
      bf16* vb = vbuf[i & 1];
      #pragma unroll
      for (int it = 0; it < 2; ++it) {
        gld16(kg[it] + (size_t)stk0 * HS_, kb + ldsoff[it]);
        gld16(vg[it] + stk0,               vb + ldsoff[it]);
      }
    }
    if (i == 0) continue;
    const int tk  = i - 1;
    const int tk0 = tk * 64;
    if (tk0 > qbase + 31) continue;
    const bf16* kb = kbuf[tk & 1];
    const bf16* vb = vbuf[tk & 1];

    floatx4 s[2][4] = {};
    __builtin_amdgcn_s_setprio(1);
    #pragma unroll
    for (int nt = 0; nt < 4; ++nt) {
      const int key = nt*16 + l16;
      #pragma unroll
      for (int ss = 0; ss < 2; ++ss) {
        short8 kf = *(const short8*)&kb[(key*8 + ((ss*4+quad) ^ x7))*8];
        s[0][nt] = MFMA16(qf[0][ss], kf, s[0][nt]);
        s[1][nt] = MFMA16(qf[1][ss], kf, s[1][nt]);
      }
    }
    __builtin_amdgcn_s_setprio(0);

    if (tk0 + 63 > qbase) {
      #pragma unroll
      for (int mt = 0; mt < 2; ++mt)
        #pragma unroll
        for (int nt = 0; nt < 4; ++nt) {
          const int key = tk0 + nt*16 + l16;
          #pragma unroll
          for (int r = 0; r < 4; ++r) {
            const int qr = qbase + mt*16 + quad*4 + r;
            if (key > qr) s[mt][nt][r] = -1e30f;
          }
        }
    }

    #pragma unroll
    for (int mt = 0; mt < 2; ++mt) {
      #pragma unroll
      for (int r = 0; r < 4; ++r) {
        const float p0 = EXP2(s[mt][0][r]), p1 = EXP2(s[mt][1][r]);
        const float p2 = EXP2(s[mt][2][r]), p3 = EXP2(s[mt][3][r]);
        lrow[mt][r] += (p0 + p1) + (p2 + p3);
        const int q = mt*16 + quad*4 + r;
        const unsigned w0 = __builtin_amdgcn_perm(__float_as_uint(p1), __float_as_uint(p0), 0x07060302u);
        const unsigned w1 = __builtin_amdgcn_perm(__float_as_uint(p3), __float_as_uint(p2), 0x07060302u);
        pw32[q*32 + (((c0 + q)     & 7) << 2) + dwl] = w0;
        pw32[q*32 + (((c0 + q + 4) & 7) << 2) + dwl] = w1;
      }
    }

    __builtin_amdgcn_s_setprio(1);
    #pragma unroll
    for (int ss = 0; ss < 2; ++ss) {
      short8 pf0 = *(const short8*)&pw[l16*64      + ((4*ss + quad + l16) & 7)*8];
      short8 pf1 = *(const short8*)&pw[(16+l16)*64 + ((4*ss + quad + l16) & 7)*8];
      #pragma unroll
      for (int nd = 0; nd < 4; ++nd) {
        const int d = nd*16 + l16;
        short8 vf = *(const short8*)&vb[(d*8 + ((ss*4+quad) ^ x7))*8];
        o[0][nd] = MFMA16(pf0, vf, o[0][nd]);
        o[1][nd] = MFMA16(pf1, vf, o[1][nd]);
      }
    }
    __builtin_amdgcn_s_setprio(0);
  }

  #pragma unroll
  for (int mt = 0; mt < 2; ++mt) {
    #pragma unroll
    for (int r = 0; r < 4; ++r) {
      float lsum = lrow[mt][r];
      lsum += __shfl_xor(lsum, 1);
      lsum += __shfl_xor(lsum, 2);
      lsum += __shfl_xor(lsum, 4);
      lsum += __shfl_xor(lsum, 8);
      const float inv = 1.0f / lsum;
      const int tt = qbase + mt*16 + quad*4 + r;
      #pragma unroll
      for (int nd = 0; nd < 4; ++nd)
        att[(size_t)(b*T_ + tt) * C_ + h*64 + nd*16 + l16] =
            __float2bfloat16(o[mt][nd][r] * inv);
    }
  }
}

extern "C" void kernel_launch(void* const* d_in, const int* in_sizes, int n_in,
                              void* d_out, int out_size, void* d_ws, size_t ws_size,
                              hipStream_t stream) {
  const float* x     = (const float*)d_in[0];
  const float* Wqkv  = (const float*)d_in[1];
  const float* Wproj = (const float*)d_in[2];
  const float* bproj = (const float*)d_in[3];
  float* out = (float*)d_out;

  char* ws = (char*)d_ws;
  bf16* xb     = (bf16*)(ws + 0);          // 8192x1024       16,777,216 B
  bf16* wqkvT  = (bf16*)(ws + 16777216);   // 3072x1024        6,291,456 B
  bf16* wprojT = (bf16*)(ws + 23068672);   // 1024x1024        2,097,152 B
  bf16* Qb     = (bf16*)(ws + 25165824);   // [B,H,T,HS]      16,777,216 B
  bf16* Kb     = (bf16*)(ws + 41943040);   // [B,H,T,HS]      16,777,216 B
  bf16* Vt     = (bf16*)(ws + 58720256);   // [B,H,HS,T] perm 16,777,216 B
  bf16* att    = (bf16*)(ws + 75497472);   // [B,T,C]         16,777,216 B

  k_prep<<<dim3(5120), 256, 0, stream>>>(x, xb, Wqkv, wqkvT, Wproj, wprojT);
  k_gemmqkv<<<dim3(256), 512, 0, stream>>>(xb, wqkvT, Qb, Kb, Vt);
  k_attn<<<dim3(1024), 256, 0, stream>>>(Qb, Kb, Vt, att);
  k_proj<8><<<dim3(512), 256, 0, stream>>>(
      att, wprojT, C_, C_, out, bproj);
}

// Round 7
// 216.704 us; speedup vs baseline: 1.0573x; 1.0042x over previous
//
#include <hip/hip_runtime.h>
#include <hip/hip_bf16.h>
#include <cstdint>
#include <cstddef>

using bf16 = __hip_bfloat16;
typedef __attribute__((ext_vector_type(8))) short short8;
typedef __attribute__((ext_vector_type(4))) float floatx4;

#define B_ 4
#define T_ 2048
#define C_ 1024
#define H_ 16
#define HS_ 64
#define BT_ (B_*T_)
#define N3C (3*C_)

#define MFMA16(a,b,c) __builtin_amdgcn_mfma_f32_16x16x32_bf16((a),(b),(c),0,0,0)

#if __has_builtin(__builtin_amdgcn_exp2f)
#define EXP2(x) __builtin_amdgcn_exp2f(x)
#else
#define EXP2(x) exp2f(x)
#endif

static __device__ __forceinline__ void gld16(const bf16* g, bf16* l) {
  __builtin_amdgcn_global_load_lds(
      (const __attribute__((address_space(1))) unsigned int*)g,
      (__attribute__((address_space(3))) unsigned int*)l, 16, 0, 0);
}

static __device__ __forceinline__ unsigned short f2bf_us(float x) {
  bf16 b = __float2bfloat16(x);
  return *(unsigned short*)&b;
}

// ---------------- fused prep: cast x + transpose-cast both weights ----------
__global__ __launch_bounds__(256)
void k_prep(const float* __restrict__ x, bf16* __restrict__ xb,
            const float* __restrict__ Wqkv, bf16* __restrict__ wqkvT,
            const float* __restrict__ Wproj, bf16* __restrict__ wprojT)
{
  const int bid = blockIdx.x, tid = threadIdx.x;
  __shared__ float tile[64][65];

  if (bid < 4096) {
    const int i = bid*256 + tid;
    const float4 v0 = ((const float4*)x)[2*i];
    const float4 v1 = ((const float4*)x)[2*i + 1];
    union { bf16 b[8]; uint4 u; } cvt;
    cvt.b[0] = __float2bfloat16(v0.x);
    cvt.b[1] = __float2bfloat16(v0.y);
    cvt.b[2] = __float2bfloat16(v0.z);
    cvt.b[3] = __float2bfloat16(v0.w);
    cvt.b[4] = __float2bfloat16(v1.x);
    cvt.b[5] = __float2bfloat16(v1.y);
    cvt.b[6] = __float2bfloat16(v1.z);
    cvt.b[7] = __float2bfloat16(v1.w);
    ((uint4*)xb)[i] = cvt.u;
    return;
  }

  const float* in; bf16* out; int N, n0, k0;
  if (bid < 4864) {
    const int j = bid - 4096;
    in = Wqkv; out = wqkvT; N = N3C;
    n0 = (j % 48) * 64; k0 = (j / 48) * 64;
  } else {
    const int j = bid - 4864;
    in = Wproj; out = wprojT; N = C_;
    n0 = (j % 16) * 64; k0 = (j / 16) * 64;
  }
  const int r = tid >> 6, c = tid & 63;
  #pragma unroll
  for (int j = 0; j < 16; ++j)
    tile[r + j*4][c] = in[(size_t)(k0 + r + j*4) * N + n0 + c];
  __syncthreads();
  #pragma unroll
  for (int j = 0; j < 16; ++j) {
    int rr = r + j*4;
    out[(size_t)(n0 + rr) * C_ + k0 + c] = __float2bfloat16(tile[c][rr]);
  }
}

// ---------------- QKV GEMM: 256x384, BK=32, 3-buf, 1-barrier/tile -----------
// R16: R15 geometry (grid 256 = 1 block/CU tail-free; BN=384 as {Q,K,V}
// 128-col groups; 8 waves 2Mx4N acc[8][6]; verified 0-conflict swizzle),
// but the schedule de-pinned per m141/m196 lessons:
//  - ONE barrier + ONE counted vmcnt per K-tile (was 6 barriers + pinned
//    lgkmcnt(0)/sched_barrier per phase). Per tile: vmcnt(5) [tile i
//    retired, i+1 in flight] -> sched_barrier(0) [no reg-op motion across
//    tile boundary] -> s_barrier -> stage A+B(i+2) -> 14 ds_read + 48 MFMA
//    in one free-scheduling window (compiler emits fine-grained lgkmcnt).
//  - Hazards: RAW = per-wave vmcnt(5) before the barrier retires tile i
//    block-wide. WAR = stage target buf[(i+2)%3] last read at tile i-1;
//    those reads retired before their MFMAs, which cannot sink past the
//    sched_barrier(0)+s_barrier tile boundary.
//  - K ascending, one MFMA per K-32 -> accumulation order unchanged.
// Epilogue identical to R15 (+ required __syncthreads before LDS reuse).
__global__ __launch_bounds__(512, 1)
void k_gemmqkv(const bf16* __restrict__ A, const bf16* __restrict__ Bt,
               bf16* __restrict__ Qb, bf16* __restrict__ Kb, bf16* __restrict__ Vt)
{
  __shared__ __align__(16) char smem[122880];
  bf16* const sA = (bf16*)smem;                 // [3][8192]  256 rows x 32
  bf16* const sB = (bf16*)(smem + 49152);       // [3][12288] 384 rows x 32

  const int tid  = threadIdx.x;
  const int lane = tid & 63, wave = tid >> 6;
  const int quad = lane >> 4, l16 = lane & 15;
  const int wm = wave >> 2, wn = wave & 3;      // 2M x 4N

  const int g = blockIdx.x;                     // 256 blocks
  const int xcd = g & 7;
  const int local = g >> 3;                     // 0..31
  const int nb = local & 7;
  const int mb = (local >> 3) * 8 + xcd;        // 0..31
  const int m0 = mb * 256;
  const int n0q = nb * 128;

  const int ra = tid >> 2;
  const int gc = (tid & 3) ^ ((ra >> 1) & 3);
  const bf16* aptr = A  + (size_t)(m0 + ra) * C_ + gc*8;
  const bf16* bp0  = Bt + (size_t)(n0q + ra) * C_ + gc*8;          // Q group
  const bf16* bp1  = Bt + (size_t)(1024 + n0q + ra) * C_ + gc*8;   // K group
  const bf16* bp2  = Bt + (size_t)(2048 + n0q + ra) * C_ + gc*8;   // V group

  floatx4 acc[8][6] = {};
  const int swz = (l16 >> 1) & 3;
  const int aoff = (wm*128 + l16)*32 + (quad ^ swz)*8;
  const int boff = (wn*96  + l16)*32 + (quad ^ swz)*8;

#define STAGE_A(t,s) { bf16* d = sA + (s)*8192;                     \
    gld16(aptr + (t)*32,                  d + tid*8);               \
    gld16(aptr + (size_t)128*C_ + (t)*32, d + 4096 + tid*8); }
#define STAGE_B(t,s) { bf16* d = sB + (s)*12288;                    \
    gld16(bp0 + (t)*32, d + tid*8);                                 \
    gld16(bp1 + (t)*32, d + 4096 + tid*8);                         \
    gld16(bp2 + (t)*32, d + 8192 + tid*8); }

  // prologue: tiles 0,1 staged (10 loads in flight; 5 per tile per wave)
  STAGE_A(0,0); STAGE_B(0,0);
  STAGE_A(1,1); STAGE_B(1,1);

  int cs = 0;                                   // i % 3
  #pragma unroll 1
  for (int i = 0; i < 32; ++i) {
    const int s2 = (cs >= 1) ? cs - 1 : 2;      // (i+2) % 3
    if (i < 31) asm volatile("s_waitcnt vmcnt(5)" ::: "memory");  // tile i done
    else        asm volatile("s_waitcnt vmcnt(0)" ::: "memory");
    __builtin_amdgcn_sched_barrier(0);          // tile boundary: no reg-op motion
    asm volatile("s_barrier" ::: "memory");
    if (i < 30) { STAGE_A(i+2, s2); STAGE_B(i+2, s2); }
    const bf16* sa = sA + cs*8192;
    const bf16* sb = sB + cs*12288;
    short8 bq[6], af[4];
    #pragma unroll
    for (int j = 0; j < 6; ++j)    bq[j]  = *(const short8*)&sb[boff + j*512];
    #pragma unroll
    for (int ii = 0; ii < 4; ++ii) af[ii] = *(const short8*)&sa[aoff + ii*512];
    __builtin_amdgcn_s_setprio(1);
    #pragma unroll
    for (int ii = 0; ii < 4; ++ii)
      #pragma unroll
      for (int j = 0; j < 6; ++j)
        acc[ii][j] = MFMA16(af[ii], bq[j], acc[ii][j]);
    __builtin_amdgcn_s_setprio(0);
    #pragma unroll
    for (int ii = 0; ii < 4; ++ii) af[ii] = *(const short8*)&sa[aoff + (4+ii)*512];
    __builtin_amdgcn_s_setprio(1);
    #pragma unroll
    for (int ii = 0; ii < 4; ++ii)
      #pragma unroll
      for (int j = 0; j < 6; ++j)
        acc[4+ii][j] = MFMA16(af[ii], bq[j], acc[4+ii][j]);
    __builtin_amdgcn_s_setprio(0);
    cs = (cs == 2) ? 0 : cs + 1;
  }
#undef STAGE_A
#undef STAGE_B

  // ---- Q/K scatter (local cols 0-255) ----
  #pragma unroll
  for (int ii = 0; ii < 8; ++ii) {
    const int rowb = m0 + wm*128 + ii*16 + quad*4;
    #pragma unroll
    for (int j = 0; j < 6; ++j) {
      const int L = wn*96 + j*16 + l16;          // 16-aligned span: uniform side
      if (L < 256) {
        const int gcol = (L < 128) ? (n0q + L) : (1024 + n0q + L - 128);
        const int h = (gcol >> 6) & 15, d = gcol & 63;
        #pragma unroll
        for (int r = 0; r < 4; ++r) {
          const int rr = rowb + r;
          const int b = rr >> 11, t = rr & 2047;
          const size_t addr = (((size_t)(b*H_ + h) * T_ + t) << 6) + d;
          if (L < 128) Qb[addr] = __float2bfloat16(acc[ii][j][r] * 0.18033688f);
          else         Kb[addr] = __float2bfloat16(acc[ii][j][r]);
        }
      }
    }
  }

  // ---- V (local cols 256-383): LDS transpose -> key-permuted Vt ----
  __syncthreads();                               // all waves done with sA/sB
  unsigned short* epi = (unsigned short*)smem;   // [128 cc][258 tl-pad]
  #pragma unroll
  for (int ii = 0; ii < 8; ++ii) {
    const int tl = wm*128 + ii*16 + quad*4;
    #pragma unroll
    for (int j = 0; j < 6; ++j) {
      const int L = wn*96 + j*16 + l16;
      if (L >= 256) {
        const int ccl = L - 256;                 // 0..127
        #pragma unroll
        for (int r = 0; r < 4; ++r)
          epi[ccl*258 + tl + r] = f2bf_us(acc[ii][j][r]);
      }
    }
  }
  __syncthreads();
  const int b  = m0 >> 11;
  const int t0 = m0 & 2047;
  #pragma unroll
  for (int it = 0; it < 32; ++it) {
    const int id = it*512 + tid;                 // 16384 dword-pairs
    const int tp = id & 31;
    const int rest = id >> 5;                    // 0..511
    const int tl64 = (rest & 3) * 64;            // 64-token group of 256 rows
    const int ccl = rest >> 2;                   // 0..127
    const int k0p = tp + (tp & 16);              // keys (k0p,k0p+16)->(2tp,2tp+1)
    const unsigned lo = epi[ccl*258 + tl64 + k0p];
    const unsigned hi = epi[ccl*258 + tl64 + k0p + 16];
    const int h = nb*2 + (ccl >> 6), d = ccl & 63;
    unsigned* row = (unsigned*)(Vt + ((size_t)(b*H_ + h) * HS_ + d) * T_);
    row[(t0 >> 1) + tl64/2 + tp] = lo | (hi << 16);
  }
}

// ---------------- proj GEMM: 128x128, BK=32, 4-deep counted-vmcnt -----------
template<int NB>
__global__ __launch_bounds__(256, 2)
void k_proj(const bf16* __restrict__ A, const bf16* __restrict__ Bt,
            int N, int K, float* __restrict__ Out, const float* __restrict__ bias)
{
  __shared__ __align__(16) char smem[65536];
  bf16* const sA = (bf16*)smem;               // [4][4096]  128 rows x 32
  bf16* const sB = (bf16*)(smem + 32768);     // [4][4096]

  const int tid  = threadIdx.x;
  const int lane = tid & 63, wave = tid >> 6;
  const int quad = lane >> 4, l16 = lane & 15;
  const int wm = wave >> 1, wn = wave & 1;

  const int g = blockIdx.x;
  const int xcd = g & 7;
  const int local = g >> 3;
  const int nb = local % NB;
  const int mb = (local / NB) * 8 + xcd;
  const int m0 = mb * 128, n0 = nb * 128;

  const int ra = tid >> 2;
  const int gc = (tid & 3) ^ ((ra >> 1) & 3);
  const bf16* aptr = A  + (size_t)(m0 + ra) * K + gc*8;
  const bf16* bptr = Bt + (size_t)(n0 + ra) * K + gc*8;
  const size_t rj = (size_t)64 * K;

  const int KT = K >> 5;                      // 32 K-tiles
  floatx4 acc[4][4] = {};
  const int swz = (l16 >> 1) & 3;
  const int aoff = (wm*64 + l16)*32 + (quad ^ swz)*8;
  const int boff = (wn*64 + l16)*32 + (quad ^ swz)*8;

  #pragma unroll
  for (int t = 0; t < 3; ++t) {
    bf16* sa = sA + t*4096; bf16* sb = sB + t*4096;
    gld16(aptr + t*32,      sa + tid*8);
    gld16(aptr + rj + t*32, sa + 2048 + tid*8);
    gld16(bptr + t*32,      sb + tid*8);
    gld16(bptr + rj + t*32, sb + 2048 + tid*8);
  }

  #pragma unroll 1
  for (int i = 0; i < KT; ++i) {
    if (i < KT-2)       asm volatile("s_waitcnt vmcnt(8)" ::: "memory");
    else if (i == KT-2) asm volatile("s_waitcnt vmcnt(4)" ::: "memory");
    else                asm volatile("s_waitcnt vmcnt(0)" ::: "memory");
    asm volatile("s_barrier" ::: "memory");
    if (i < KT-3) {
      const int t = i + 3;
      bf16* sa = sA + (t & 3)*4096; bf16* sb = sB + (t & 3)*4096;
      gld16(aptr + t*32,      sa + tid*8);
      gld16(aptr + rj + t*32, sa + 2048 + tid*8);
      gld16(bptr + t*32,      sb + tid*8);
      gld16(bptr + rj + t*32, sb + 2048 + tid*8);
    }
    const bf16* sa = sA + (i & 3)*4096;
    const bf16* sb = sB + (i & 3)*4096;
    short8 af[4], bfm[4];
    #pragma unroll
    for (int ii = 0; ii < 4; ++ii) af[ii]  = *(const short8*)&sa[aoff + ii*512];
    #pragma unroll
    for (int j = 0; j < 4; ++j)    bfm[j]  = *(const short8*)&sb[boff + j*512];
    __builtin_amdgcn_s_setprio(1);
    #pragma unroll
    for (int ii = 0; ii < 4; ++ii)
      #pragma unroll
      for (int j = 0; j < 4; ++j)
        acc[ii][j] = MFMA16(af[ii], bfm[j], acc[ii][j]);
    __builtin_amdgcn_s_setprio(0);
  }

  #pragma unroll
  for (int i = 0; i < 4; ++i) {
    const int rowb = m0 + wm*64 + i*16 + quad*4;
    #pragma unroll
    for (int j = 0; j < 4; ++j) {
      const int col = n0 + wn*64 + j*16 + l16;
      #pragma unroll
      for (int r = 0; r < 4; ++r)
        Out[(size_t)(rowb + r) * N + col] = acc[i][j][r] + bias[col];
    }
  }
}

// ---------------- flash attention (causal) ----------------------------------
__global__ __launch_bounds__(256, 3)
void k_attn(const bf16* __restrict__ Q, const bf16* __restrict__ K,
            const bf16* __restrict__ Vt, bf16* __restrict__ att)
{
  __shared__ bf16 kbuf[2][64*64];   // [buf][key][dc^key&7]
  __shared__ bf16 vbuf[2][64*64];   // [buf][d][pc^d&7]  (positions, permuted)
  __shared__ bf16 pbuf[4][32*64];   // per-wave [q][(pc+q)&7 rotation]

  const int tid  = threadIdx.x;
  const int lane = tid & 63, wave = tid >> 6;
  const int quad = lane >> 4, l16 = lane & 15;
  const int x7 = l16 & 7;

  const int g  = blockIdx.x;              // 1024 blocks
  const int bh = (g & 7) * 8 + ((g >> 3) & 7);  // 16 blocks of a bh share XCD g&7
  const int qt = 15 - (g >> 6);           // q-tile index; heavy (qt=15) first
  const int b = bh >> 4, h = bh & 15;

  const bf16* Qp = Q  + (size_t)bh * T_ * HS_;
  const bf16* Kp = K  + (size_t)bh * T_ * HS_;
  const bf16* Vp = Vt + (size_t)bh * HS_ * T_;

  const int qbase = qt*128 + wave*32;
  const int ntk = 2*qt + 2;               // key tiles to process

  short8 qf[2][2];
  #pragma unroll
  for (int mt = 0; mt < 2; ++mt)
    #pragma unroll
    for (int ss = 0; ss < 2; ++ss)
      qf[mt][ss] = *(const short8*)(Qp + (size_t)(qbase + mt*16 + l16) * HS_ + ss*32 + quad*8);

  floatx4 o[2][4] = {};
  float lrow[2][4] = {};

  const bf16* kg[2]; const bf16* vg[2];
  int ldsoff[2];
  #pragma unroll
  for (int it = 0; it < 2; ++it) {
    const int c = it*256 + tid;
    const int row = c >> 3;
    const int col = (c & 7) ^ (row & 7);
    kg[it] = Kp + (size_t)row * HS_ + col*8;
    vg[it] = Vp + (size_t)row * T_ + col*8;
    ldsoff[it] = c*8;
  }

  bf16* pw = pbuf[wave];
  unsigned int* pw32 = (unsigned int*)pw;
  const int c0 = l16 >> 2;
  const int dwl = l16 & 3;

  for (int i = 0; i <= ntk; ++i) {
    __syncthreads();
    if (i < ntk) {
      const int stk0 = i * 64;
      bf16* kb = kbuf[i & 1];
      bf16* vb = vbuf[i & 1];
      #pragma unroll
      for (int it = 0; it < 2; ++it) {
        gld16(kg[it] + (size_t)stk0 * HS_, kb + ldsoff[it]);
        gld16(vg[it] + stk0,               vb + ldsoff[it]);
      }
    }
    if (i == 0) continue;
    const int tk  = i - 1;
    const int tk0 = tk * 64;
    if (tk0 > qbase + 31) continue;
    const bf16* kb = kbuf[tk & 1];
    const bf16* vb = vbuf[tk & 1];

    floatx4 s[2][4] = {};
    __builtin_amdgcn_s_setprio(1);
    #pragma unroll
    for (int nt = 0; nt < 4; ++nt) {
      const int key = nt*16 + l16;
      #pragma unroll
      for (int ss = 0; ss < 2; ++ss) {
        short8 kf = *(const short8*)&kb[(key*8 + ((ss*4+quad) ^ x7))*8];
        s[0][nt] = MFMA16(qf[0][ss], kf, s[0][nt]);
        s[1][nt] = MFMA16(qf[1][ss], kf, s[1][nt]);
      }
    }
    __builtin_amdgcn_s_setprio(0);

    if (tk0 + 63 > qbase) {
      #pragma unroll
      for (int mt = 0; mt < 2; ++mt)
        #pragma unroll
        for (int nt = 0; nt < 4; ++nt) {
          const int key = tk0 + nt*16 + l16;
          #pragma unroll
          for (int r = 0; r < 4; ++r) {
            const int qr = qbase + mt*16 + quad*4 + r;
            if (key > qr) s[mt][nt][r] = -1e30f;
          }
        }
    }

    #pragma unroll
    for (int mt = 0; mt < 2; ++mt) {
      #pragma unroll
      for (int r = 0; r < 4; ++r) {
        const float p0 = EXP2(s[mt][0][r]), p1 = EXP2(s[mt][1][r]);
        const float p2 = EXP2(s[mt][2][r]), p3 = EXP2(s[mt][3][r]);
        lrow[mt][r] += (p0 + p1) + (p2 + p3);
        const int q = mt*16 + quad*4 + r;
        const unsigned w0 = __builtin_amdgcn_perm(__float_as_uint(p1), __float_as_uint(p0), 0x07060302u);
        const unsigned w1 = __builtin_amdgcn_perm(__float_as_uint(p3), __float_as_uint(p2), 0x07060302u);
        pw32[q*32 + (((c0 + q)     & 7) << 2) + dwl] = w0;
        pw32[q*32 + (((c0 + q + 4) & 7) << 2) + dwl] = w1;
      }
    }

    __builtin_amdgcn_s_setprio(1);
    #pragma unroll
    for (int ss = 0; ss < 2; ++ss) {
      short8 pf0 = *(const short8*)&pw[l16*64      + ((4*ss + quad + l16) & 7)*8];
      short8 pf1 = *(const short8*)&pw[(16+l16)*64 + ((4*ss + quad + l16) & 7)*8];
      #pragma unroll
      for (int nd = 0; nd < 4; ++nd) {
        const int d = nd*16 + l16;
        short8 vf = *(const short8*)&vb[(d*8 + ((ss*4+quad) ^ x7))*8];
        o[0][nd] = MFMA16(pf0, vf, o[0][nd]);
        o[1][nd] = MFMA16(pf1, vf, o[1][nd]);
      }
    }
    __builtin_amdgcn_s_setprio(0);
  }

  #pragma unroll
  for (int mt = 0; mt < 2; ++mt) {
    #pragma unroll
    for (int r = 0; r < 4; ++r) {
      float lsum = lrow[mt][r];
      lsum += __shfl_xor(lsum, 1);
      lsum += __shfl_xor(lsum, 2);
      lsum += __shfl_xor(lsum, 4);
      lsum += __shfl_xor(lsum, 8);
      const float inv = 1.0f / lsum;
      const int tt = qbase + mt*16 + quad*4 + r;
      #pragma unroll
      for (int nd = 0; nd < 4; ++nd)
        att[(size_t)(b*T_ + tt) * C_ + h*64 + nd*16 + l16] =
            __float2bfloat16(o[mt][nd][r] * inv);
    }
  }
}

extern "C" void kernel_launch(void* const* d_in, const int* in_sizes, int n_in,
                              void* d_out, int out_size, void* d_ws, size_t ws_size,
                              hipStream_t stream) {
  const float* x     = (const float*)d_in[0];
  const float* Wqkv  = (const float*)d_in[1];
  const float* Wproj = (const float*)d_in[2];
  const float* bproj = (const float*)d_in[3];
  float* out = (float*)d_out;

  char* ws = (char*)d_ws;
  bf16* xb     = (bf16*)(ws + 0);          // 8192x1024       16,777,216 B
  bf16* wqkvT  = (bf16*)(ws + 16777216);   // 3072x1024        6,291,456 B
  bf16* wprojT = (bf16*)(ws + 23068672);   // 1024x1024        2,097,152 B
  bf16* Qb     = (bf16*)(ws + 25165824);   // [B,H,T,HS]      16,777,216 B
  bf16* Kb     = (bf16*)(ws + 41943040);   // [B,H,T,HS]      16,777,216 B
  bf16* Vt     = (bf16*)(ws + 58720256);   // [B,H,HS,T] perm 16,777,216 B
  bf16* att    = (bf16*)(ws + 75497472);   // [B,T,C]         16,777,216 B

  k_prep<<<dim3(5120), 256, 0, stream>>>(x, xb, Wqkv, wqkvT, Wproj, wprojT);
  k_gemmqkv<<<dim3(256), 512, 0, stream>>>(xb, wqkvT, Qb, Kb, Vt);
  k_attn<<<dim3(1024), 256, 0, stream>>>(Qb, Kb, Vt, att);
  k_proj<8><<<dim3(512), 256, 0, stream>>>(
      att, wprojT, C_, C_, out, bproj);
}